// Round 1
// baseline (250.531 us; speedup 1.0000x reference)
//
#include <hip/hip_runtime.h>

#define B_    4
#define N1_   16384
#define N2_   4096
#define C1_   64
#define C2_   128
#define BQ    64            // queries per block
#define CHUNK (N2_ / 4)     // candidates per wave in phase 1

typedef __attribute__((ext_vector_type(8))) short bf16x8;
typedef __attribute__((ext_vector_type(4))) float f32x4;
typedef __attribute__((ext_vector_type(4))) unsigned short u16x4;

__device__ __forceinline__ unsigned short f2bf(float f) {
  unsigned int u = __builtin_bit_cast(unsigned int, f);
  unsigned int r = (u + 0x7FFFu + ((u >> 16) & 1u)) >> 16;
  return (unsigned short)r;
}

// ---- prep: pack candidates (x,y,z,-0.5*|c|^2), transpose W1/W2 to bf16, copy biases ----
__global__ void prep_kernel(const float* __restrict__ xyz2, const float* __restrict__ W1,
                            const float* __restrict__ b1, const float* __restrict__ W2,
                            const float* __restrict__ b2,
                            float4* __restrict__ cand, unsigned short* __restrict__ w1t,
                            unsigned short* __restrict__ w2t, float* __restrict__ bb1,
                            float* __restrict__ bb2) {
  int t = blockIdx.x * 256 + threadIdx.x;
  const int NC  = B_ * N2_;     // 16384
  const int NW1 = 192 * 128;    // 24576
  const int NW2 = 128 * 128;    // 16384
  if (t < NC) {
    float x = xyz2[t * 3 + 0], y = xyz2[t * 3 + 1], z = xyz2[t * 3 + 2];
    cand[t] = make_float4(x, y, z, -0.5f * (x * x + y * y + z * z));
  } else if (t < NC + NW1) {
    int i = t - NC; int k = i >> 7, c = i & 127;
    w1t[c * 192 + k] = f2bf(W1[i]);
  } else if (t < NC + NW1 + NW2) {
    int i = t - NC - NW1; int k = i >> 7, c = i & 127;
    w2t[c * 128 + k] = f2bf(W2[i]);
  } else if (t < NC + NW1 + NW2 + 128) {
    int i = t - NC - NW1 - NW2; bb1[i] = b1[i];
  } else if (t < NC + NW1 + NW2 + 256) {
    int i = t - NC - NW1 - NW2 - 128; bb2[i] = b2[i];
  }
}

// ---- fused: three_nn + interp + concat + MLP(192->128->128) ----
__global__ __launch_bounds__(256, 2) void fused_kernel(
    const float* __restrict__ xyz1, const float* __restrict__ points1,
    const float* __restrict__ points2, const float4* __restrict__ cand,
    const unsigned short* __restrict__ w1t, const unsigned short* __restrict__ w2t,
    const float* __restrict__ bb1, const float* __restrict__ bb2,
    float* __restrict__ out) {

  __shared__ unsigned short Ash[BQ][200];   // 64 x 192 bf16, padded stride 200
  __shared__ unsigned short Hsh[BQ][136];   // 64 x 128 bf16, padded stride 136
  __shared__ float sS[4][BQ][3];
  __shared__ int   sI[4][BQ][3];
  __shared__ float sW[BQ][3];
  __shared__ int   sJ[BQ][3];
  __shared__ float sB1[128], sB2[128];

  const int tid  = threadIdx.x;
  const int lane = tid & 63;
  const int wv   = __builtin_amdgcn_readfirstlane(tid >> 6);
  const int bid  = blockIdx.x;
  const int bb   = bid >> 8;            // N1_/BQ = 256 blocks per batch
  const int n0   = (bid & 255) * BQ;

  if (tid < 128) sB1[tid] = bb1[tid];
  else           sB2[tid - 128] = bb2[tid - 128];

  // ---------- phase 1: per-wave top-3 over its candidate chunk ----------
  const int q = n0 + lane;
  const float* xp = xyz1 + ((size_t)bb * N1_ + q) * 3;
  const float x = xp[0], y = xp[1], z = xp[2];
  const float q1 = fmaf(x, x, fmaf(y, y, z * z));
  const float4* cb = cand + (size_t)bb * N2_;
  const int jbase = wv * CHUNK;

  float s0 = -3.4e38f, s1 = -3.4e38f, s2 = -3.4e38f;
  int   i0 = 0, i1 = 0, i2 = 0;
  for (int j = 0; j < CHUNK; j += 4) {
    #pragma unroll
    for (int u = 0; u < 4; ++u) {
      const int jj = jbase + j + u;
      const float4 cp = cb[jj];
      const float s = fmaf(x, cp.x, fmaf(y, cp.y, fmaf(z, cp.z, cp.w)));
      if (s > s2) {
        const bool g1 = s > s1, g0 = s > s0;
        s2 = g1 ? s1 : s;             i2 = g1 ? i1 : jj;
        s1 = g1 ? (g0 ? s0 : s) : s1; i1 = g1 ? (g0 ? i0 : jj) : i1;
        s0 = g0 ? s : s0;             i0 = g0 ? jj : i0;
      }
    }
  }
  sS[wv][lane][0] = s0; sS[wv][lane][1] = s1; sS[wv][lane][2] = s2;
  sI[wv][lane][0] = i0; sI[wv][lane][1] = i1; sI[wv][lane][2] = i2;
  __syncthreads();

  // ---------- phase 2: merge 4 partial top-3s, compute weights ----------
  if (tid < BQ) {
    float m0 = -3.4e38f, m1 = -3.4e38f, m2 = -3.4e38f;
    int   j0 = 0, j1 = 0, j2 = 0;
    #pragma unroll
    for (int w = 0; w < 4; ++w) {
      #pragma unroll
      for (int r = 0; r < 3; ++r) {
        const float s = sS[w][tid][r]; const int jj = sI[w][tid][r];
        if (s > m2) {
          const bool g1 = s > m1, g0 = s > m0;
          m2 = g1 ? m1 : s;             j2 = g1 ? j1 : jj;
          m1 = g1 ? (g0 ? m0 : s) : m1; j1 = g1 ? (g0 ? j0 : jj) : j1;
          m0 = g0 ? s : m0;             j0 = g0 ? jj : j0;
        }
      }
    }
    const float d0 = fmaxf(fmaf(-2.f, m0, q1), 1e-10f);
    const float d1 = fmaxf(fmaf(-2.f, m1, q1), 1e-10f);
    const float d2 = fmaxf(fmaf(-2.f, m2, q1), 1e-10f);
    const float r0 = 1.f / d0, r1 = 1.f / d1, r2 = 1.f / d2;
    const float norm = r0 + r1 + r2;
    sW[tid][0] = r0 / norm; sW[tid][1] = r1 / norm; sW[tid][2] = r2 / norm;
    sJ[tid][0] = j0; sJ[tid][1] = j1; sJ[tid][2] = j2;
  }
  __syncthreads();

  // ---------- phase 3: gather + interpolate + concat into bf16 A tile ----------
  {
    const int qq = tid >> 2, cq = tid & 3;    // 4 threads per query
    const float w0 = sW[qq][0], w1 = sW[qq][1], w2 = sW[qq][2];
    const float* f0 = points2 + ((size_t)bb * N2_ + sJ[qq][0]) * C2_;
    const float* f1 = points2 + ((size_t)bb * N2_ + sJ[qq][1]) * C2_;
    const float* f2 = points2 + ((size_t)bb * N2_ + sJ[qq][2]) * C2_;
    #pragma unroll
    for (int c = cq * 32; c < cq * 32 + 32; c += 4) {
      const float4 a  = *(const float4*)(f0 + c);
      const float4 bv = *(const float4*)(f1 + c);
      const float4 cv = *(const float4*)(f2 + c);
      u16x4 pk;
      pk.x = f2bf(fmaf(w2, cv.x, fmaf(w1, bv.x, w0 * a.x)));
      pk.y = f2bf(fmaf(w2, cv.y, fmaf(w1, bv.y, w0 * a.y)));
      pk.z = f2bf(fmaf(w2, cv.z, fmaf(w1, bv.z, w0 * a.z)));
      pk.w = f2bf(fmaf(w2, cv.w, fmaf(w1, bv.w, w0 * a.w)));
      *(u16x4*)&Ash[qq][c] = pk;
    }
    const float* p1 = points1 + ((size_t)bb * N1_ + n0 + qq) * C1_;
    #pragma unroll
    for (int c = cq * 16; c < cq * 16 + 16; c += 4) {
      const float4 v = *(const float4*)(p1 + c);
      u16x4 pk;
      pk.x = f2bf(v.x); pk.y = f2bf(v.y); pk.z = f2bf(v.z); pk.w = f2bf(v.w);
      *(u16x4*)&Ash[qq][128 + c] = pk;
    }
  }
  __syncthreads();

  // ---------- phase 4: GEMM1  (64x192) x (192x128), wave = 32-col slice ----------
  const int lr = lane & 15;
  const int lg = lane >> 4;
  const int c0 = wv * 32;
  f32x4 acc[4][2];
  #pragma unroll
  for (int m = 0; m < 4; ++m)
    #pragma unroll
    for (int n = 0; n < 2; ++n)
      acc[m][n] = (f32x4){0.f, 0.f, 0.f, 0.f};

  #pragma unroll
  for (int kk = 0; kk < 6; ++kk) {
    const int kof = kk * 32 + lg * 8;
    bf16x8 bfr[2];
    #pragma unroll
    for (int n = 0; n < 2; ++n) {
      const int col = c0 + n * 16 + lr;
      bfr[n] = *(const bf16x8*)(w1t + (size_t)col * 192 + kof);
    }
    #pragma unroll
    for (int m = 0; m < 4; ++m) {
      const bf16x8 af = *(const bf16x8*)&Ash[m * 16 + lr][kof];
      #pragma unroll
      for (int n = 0; n < 2; ++n)
        acc[m][n] = __builtin_amdgcn_mfma_f32_16x16x32_bf16(af, bfr[n], acc[m][n], 0, 0, 0);
    }
  }
  #pragma unroll
  for (int m = 0; m < 4; ++m) {
    #pragma unroll
    for (int n = 0; n < 2; ++n) {
      const int col = c0 + n * 16 + lr;
      const float bias = sB1[col];
      #pragma unroll
      for (int e = 0; e < 4; ++e) {
        const int row = m * 16 + lg * 4 + e;
        Hsh[row][col] = f2bf(fmaxf(acc[m][n][e] + bias, 0.f));
      }
    }
  }
  __syncthreads();

  // ---------- phase 5: GEMM2  (64x128) x (128x128), relu, store f32 ----------
  f32x4 acc2[4][2];
  #pragma unroll
  for (int m = 0; m < 4; ++m)
    #pragma unroll
    for (int n = 0; n < 2; ++n)
      acc2[m][n] = (f32x4){0.f, 0.f, 0.f, 0.f};

  #pragma unroll
  for (int kk = 0; kk < 4; ++kk) {
    const int kof = kk * 32 + lg * 8;
    bf16x8 bfr[2];
    #pragma unroll
    for (int n = 0; n < 2; ++n) {
      const int col = c0 + n * 16 + lr;
      bfr[n] = *(const bf16x8*)(w2t + (size_t)col * 128 + kof);
    }
    #pragma unroll
    for (int m = 0; m < 4; ++m) {
      const bf16x8 af = *(const bf16x8*)&Hsh[m * 16 + lr][kof];
      #pragma unroll
      for (int n = 0; n < 2; ++n)
        acc2[m][n] = __builtin_amdgcn_mfma_f32_16x16x32_bf16(af, bfr[n], acc2[m][n], 0, 0, 0);
    }
  }
  #pragma unroll
  for (int m = 0; m < 4; ++m) {
    #pragma unroll
    for (int n = 0; n < 2; ++n) {
      const int col = c0 + n * 16 + lr;
      const float bias = sB2[col];
      #pragma unroll
      for (int e = 0; e < 4; ++e) {
        const int row = m * 16 + lg * 4 + e;
        out[((size_t)bb * N1_ + n0 + row) * 128 + col] = fmaxf(acc2[m][n][e] + bias, 0.f);
      }
    }
  }
}

extern "C" void kernel_launch(void* const* d_in, const int* in_sizes, int n_in,
                              void* d_out, int out_size, void* d_ws, size_t ws_size,
                              hipStream_t stream) {
  const float* xyz1    = (const float*)d_in[0];
  const float* xyz2    = (const float*)d_in[1];
  const float* points1 = (const float*)d_in[2];
  const float* points2 = (const float*)d_in[3];
  const float* W1      = (const float*)d_in[4];
  const float* b1      = (const float*)d_in[5];
  const float* W2      = (const float*)d_in[6];
  const float* b2      = (const float*)d_in[7];
  float* out = (float*)d_out;

  char* ws = (char*)d_ws;
  float4*         cand = (float4*)ws;                        // 4*4096*16   = 262144 B
  unsigned short* w1t  = (unsigned short*)(ws + 262144);     // 192*128*2   =  49152 B
  unsigned short* w2t  = (unsigned short*)(ws + 311296);     // 128*128*2   =  32768 B
  float*          bb1  = (float*)(ws + 344064);              // 512 B
  float*          bb2  = (float*)(ws + 344576);              // 512 B

  prep_kernel<<<225, 256, 0, stream>>>(xyz2, W1, b1, W2, b2, cand, w1t, w2t, bb1, bb2);
  fused_kernel<<<1024, 256, 0, stream>>>(xyz1, points1, points2, cand, w1t, w2t, bb1, bb2, out);
}

// Round 3
// 138.083 us; speedup vs baseline: 1.8144x; 1.8144x over previous
//
#include <hip/hip_runtime.h>

#define B_    4
#define N1_   16384
#define N2_   4096
#define C1_   64
#define C2_   128
#define BQ    64            // queries per block
#define CHUNK (N2_ / 4)     // candidates per wave in phase 1

typedef __attribute__((ext_vector_type(8))) short bf16x8;
typedef __attribute__((ext_vector_type(4))) float f32x4;
typedef __attribute__((ext_vector_type(4))) unsigned short u16x4;

__device__ __forceinline__ unsigned short f2bf(float f) {
  unsigned int u = __builtin_bit_cast(unsigned int, f);
  unsigned int r = (u + 0x7FFFu + ((u >> 16) & 1u)) >> 16;
  return (unsigned short)r;
}

// insert 64-bit lexicographic key x into sorted triple m0<=m1<=m2 (keep 3 smallest)
// fmin/fmax f64 -> v_min_f64/v_max_f64: branchless, no vcc dependency
#define INS3D(x, m0, m1, m2) do {           \
    double _a = fmax((x), (m0));            \
    (m0) = fmin((x), (m0));                 \
    double _b = fmax(_a, (m1));             \
    (m1) = fmin(_a, (m1));                  \
    (m2) = fmin(_b, (m2));                  \
  } while (0)

#define KINF __builtin_bit_cast(double, 0x7FF0000000000000ULL)

// ---- prep: pack candidates (-2x,-2y,-2z,|c|^2), transpose W1/W2 to bf16 ----
__global__ void prep_kernel(const float* __restrict__ xyz2, const float* __restrict__ W1,
                            const float* __restrict__ W2,
                            float4* __restrict__ cand, unsigned short* __restrict__ w1t,
                            unsigned short* __restrict__ w2t) {
  int t = blockIdx.x * 256 + threadIdx.x;
  const int NC  = B_ * N2_;     // 16384
  const int NW1 = 192 * 128;    // 24576
  const int NW2 = 128 * 128;    // 16384
  if (t < NC) {
    float x = xyz2[t * 3 + 0], y = xyz2[t * 3 + 1], z = xyz2[t * 3 + 2];
    cand[t] = make_float4(-2.f * x, -2.f * y, -2.f * z, x * x + y * y + z * z);
  } else if (t < NC + NW1) {
    int i = t - NC; int k = i >> 7, c = i & 127;
    w1t[c * 192 + k] = f2bf(W1[i]);
  } else if (t < NC + NW1 + NW2) {
    int i = t - NC - NW1; int k = i >> 7, c = i & 127;
    w2t[c * 128 + k] = f2bf(W2[i]);
  }
}

// ---- fused: three_nn + interp + concat + MLP(192->128->128) ----
__global__ __launch_bounds__(256, 4) void fused_kernel(
    const float* __restrict__ xyz1, const float* __restrict__ points1,
    const float* __restrict__ points2, const float4* __restrict__ cand,
    const unsigned short* __restrict__ w1t, const unsigned short* __restrict__ w2t,
    const float* __restrict__ bb1, const float* __restrict__ bb2,
    float* __restrict__ out) {

  // union: Ptop (phase1-2) -> Ash (phase3-4) -> Hsh (phase4-5); 25600 B total
  __shared__ __align__(16) unsigned char Ubuf[BQ * 200 * 2];
  unsigned short (*Ash)[200]  = (unsigned short (*)[200])Ubuf;
  double (*Ptop)[BQ][3]       = (double (*)[BQ][3])Ubuf;   // [4][64][3] = 6144 B
  unsigned short (*Hsh)[136]  = (unsigned short (*)[136])Ubuf;
  __shared__ float sW[BQ][3];
  __shared__ int   sJ[BQ][3];

  const int tid  = threadIdx.x;
  const int lane = tid & 63;
  const int wv   = __builtin_amdgcn_readfirstlane(tid >> 6);
  const int bid  = blockIdx.x;
  const int bb   = bid >> 8;            // 256 blocks per batch
  const int n0   = (bid & 255) * BQ;

  // ---------- phase 1: per-wave exact top-3 over its candidate chunk ----------
  const int q = n0 + lane;
  const float* xp = xyz1 + ((size_t)bb * N1_ + q) * 3;
  const float x = xp[0], y = xp[1], z = xp[2];
  const float q1 = fmaf(x, x, fmaf(y, y, z * z));
  const float4* cb = cand + (size_t)bb * N2_;
  const int jbase = wv * CHUNK;

  // 4 independent top-3 streams; key = (d_bits << 32) | idx as double (lexicographic)
  double k0[4], k1[4], k2[4];
  #pragma unroll
  for (int s = 0; s < 4; ++s) { k0[s] = KINF; k1[s] = KINF; k2[s] = KINF; }

  for (int j = 0; j < CHUNK; j += 16) {
    float4 cp[16];
    #pragma unroll
    for (int u = 0; u < 16; ++u) cp[u] = cb[jbase + j + u];
    #pragma unroll
    for (int u = 0; u < 16; ++u) {
      const int s = u & 3;
      // d = |q|^2 - 2 q.c + |c|^2  (cand pre-scaled by -2)
      const float d = fmaf(cp[u].x, x, fmaf(cp[u].y, y, fmaf(cp[u].z, z, q1 + cp[u].w)));
      const unsigned long long kk =
          ((unsigned long long)__builtin_bit_cast(unsigned, d) << 32)
          | (unsigned)(jbase + j + u);
      const double xk = __builtin_bit_cast(double, kk);
      INS3D(xk, k0[s], k1[s], k2[s]);
    }
  }
  // merge 4 streams -> stream 0
  #pragma unroll
  for (int s = 1; s < 4; ++s) {
    INS3D(k0[s], k0[0], k1[0], k2[0]);
    INS3D(k1[s], k0[0], k1[0], k2[0]);
    INS3D(k2[s], k0[0], k1[0], k2[0]);
  }
  Ptop[wv][lane][0] = k0[0]; Ptop[wv][lane][1] = k1[0]; Ptop[wv][lane][2] = k2[0];
  __syncthreads();

  // ---------- phase 2: merge 4 waves' top-3, compute weights ----------
  if (tid < BQ) {
    double m0 = KINF, m1 = KINF, m2 = KINF;
    #pragma unroll
    for (int w = 0; w < 4; ++w)
      #pragma unroll
      for (int r = 0; r < 3; ++r) {
        const double xk = Ptop[w][tid][r];
        INS3D(xk, m0, m1, m2);
      }
    const unsigned long long u0 = __builtin_bit_cast(unsigned long long, m0);
    const unsigned long long u1 = __builtin_bit_cast(unsigned long long, m1);
    const unsigned long long u2 = __builtin_bit_cast(unsigned long long, m2);
    const float d0 = fmaxf(__builtin_bit_cast(float, (unsigned)(u0 >> 32)), 1e-10f);
    const float d1 = fmaxf(__builtin_bit_cast(float, (unsigned)(u1 >> 32)), 1e-10f);
    const float d2 = fmaxf(__builtin_bit_cast(float, (unsigned)(u2 >> 32)), 1e-10f);
    const float r0 = 1.f / d0, r1 = 1.f / d1, r2 = 1.f / d2;
    const float inorm = 1.f / (r0 + r1 + r2);
    sW[tid][0] = r0 * inorm; sW[tid][1] = r1 * inorm; sW[tid][2] = r2 * inorm;
    sJ[tid][0] = (int)(unsigned)u0; sJ[tid][1] = (int)(unsigned)u1; sJ[tid][2] = (int)(unsigned)u2;
  }
  __syncthreads();

  // ---------- phase 3: gather + interpolate + concat into bf16 A tile ----------
  {
    const int qq = tid >> 2, cq = tid & 3;    // 4 threads per query
    const float w0 = sW[qq][0], w1 = sW[qq][1], w2 = sW[qq][2];
    const float* f0 = points2 + ((size_t)bb * N2_ + sJ[qq][0]) * C2_;
    const float* f1 = points2 + ((size_t)bb * N2_ + sJ[qq][1]) * C2_;
    const float* f2 = points2 + ((size_t)bb * N2_ + sJ[qq][2]) * C2_;
    #pragma unroll
    for (int c = cq * 32; c < cq * 32 + 32; c += 4) {
      const float4 a  = *(const float4*)(f0 + c);
      const float4 bv = *(const float4*)(f1 + c);
      const float4 cv = *(const float4*)(f2 + c);
      u16x4 pk;
      pk.x = f2bf(fmaf(w2, cv.x, fmaf(w1, bv.x, w0 * a.x)));
      pk.y = f2bf(fmaf(w2, cv.y, fmaf(w1, bv.y, w0 * a.y)));
      pk.z = f2bf(fmaf(w2, cv.z, fmaf(w1, bv.z, w0 * a.z)));
      pk.w = f2bf(fmaf(w2, cv.w, fmaf(w1, bv.w, w0 * a.w)));
      *(u16x4*)&Ash[qq][c] = pk;
    }
    const float* p1 = points1 + ((size_t)bb * N1_ + n0 + qq) * C1_;
    #pragma unroll
    for (int c = cq * 16; c < cq * 16 + 16; c += 4) {
      const float4 v = *(const float4*)(p1 + c);
      u16x4 pk;
      pk.x = f2bf(v.x); pk.y = f2bf(v.y); pk.z = f2bf(v.z); pk.w = f2bf(v.w);
      *(u16x4*)&Ash[qq][128 + c] = pk;
    }
  }
  __syncthreads();

  // ---------- phase 4: GEMM1  (64x192) x (192x128), wave = 32-col slice ----------
  const int lr = lane & 15;
  const int lg = lane >> 4;
  const int c0 = wv * 32;
  f32x4 acc[4][2];
  #pragma unroll
  for (int m = 0; m < 4; ++m)
    #pragma unroll
    for (int n = 0; n < 2; ++n)
      acc[m][n] = (f32x4){0.f, 0.f, 0.f, 0.f};

  #pragma unroll
  for (int kk = 0; kk < 6; ++kk) {
    const int kof = kk * 32 + lg * 8;
    bf16x8 bfr[2];
    #pragma unroll
    for (int n = 0; n < 2; ++n) {
      const int col = c0 + n * 16 + lr;
      bfr[n] = *(const bf16x8*)(w1t + (size_t)col * 192 + kof);
    }
    #pragma unroll
    for (int m = 0; m < 4; ++m) {
      const bf16x8 af = *(const bf16x8*)&Ash[m * 16 + lr][kof];
      #pragma unroll
      for (int n = 0; n < 2; ++n)
        acc[m][n] = __builtin_amdgcn_mfma_f32_16x16x32_bf16(af, bfr[n], acc[m][n], 0, 0, 0);
    }
  }
  __syncthreads();   // all waves done READING Ash before H overwrites the union

  #pragma unroll
  for (int m = 0; m < 4; ++m) {
    #pragma unroll
    for (int n = 0; n < 2; ++n) {
      const int col = c0 + n * 16 + lr;
      const float bias = bb1[col];
      #pragma unroll
      for (int e = 0; e < 4; ++e) {
        const int row = m * 16 + lg * 4 + e;
        Hsh[row][col] = f2bf(fmaxf(acc[m][n][e] + bias, 0.f));
      }
    }
  }
  __syncthreads();

  // ---------- phase 5: GEMM2  (64x128) x (128x128), relu, store f32 ----------
  f32x4 acc2[4][2];
  #pragma unroll
  for (int m = 0; m < 4; ++m)
    #pragma unroll
    for (int n = 0; n < 2; ++n)
      acc2[m][n] = (f32x4){0.f, 0.f, 0.f, 0.f};

  #pragma unroll
  for (int kk = 0; kk < 4; ++kk) {
    const int kof = kk * 32 + lg * 8;
    bf16x8 bfr[2];
    #pragma unroll
    for (int n = 0; n < 2; ++n) {
      const int col = c0 + n * 16 + lr;
      bfr[n] = *(const bf16x8*)(w2t + (size_t)col * 128 + kof);
    }
    #pragma unroll
    for (int m = 0; m < 4; ++m) {
      const bf16x8 af = *(const bf16x8*)&Hsh[m * 16 + lr][kof];
      #pragma unroll
      for (int n = 0; n < 2; ++n)
        acc2[m][n] = __builtin_amdgcn_mfma_f32_16x16x32_bf16(af, bfr[n], acc2[m][n], 0, 0, 0);
    }
  }
  #pragma unroll
  for (int m = 0; m < 4; ++m) {
    #pragma unroll
    for (int n = 0; n < 2; ++n) {
      const int col = c0 + n * 16 + lr;
      const float bias = bb2[col];
      #pragma unroll
      for (int e = 0; e < 4; ++e) {
        const int row = m * 16 + lg * 4 + e;
        out[((size_t)bb * N1_ + n0 + row) * 128 + col] = fmaxf(acc2[m][n][e] + bias, 0.f);
      }
    }
  }
}

extern "C" void kernel_launch(void* const* d_in, const int* in_sizes, int n_in,
                              void* d_out, int out_size, void* d_ws, size_t ws_size,
                              hipStream_t stream) {
  const float* xyz1    = (const float*)d_in[0];
  const float* xyz2    = (const float*)d_in[1];
  const float* points1 = (const float*)d_in[2];
  const float* points2 = (const float*)d_in[3];
  const float* W1      = (const float*)d_in[4];
  const float* b1      = (const float*)d_in[5];
  const float* W2      = (const float*)d_in[6];
  const float* b2      = (const float*)d_in[7];
  float* out = (float*)d_out;

  char* ws = (char*)d_ws;
  float4*         cand = (float4*)ws;                        // 4*4096*16   = 262144 B
  unsigned short* w1t  = (unsigned short*)(ws + 262144);     // 192*128*2   =  49152 B
  unsigned short* w2t  = (unsigned short*)(ws + 311296);     // 128*128*2   =  32768 B

  prep_kernel<<<224, 256, 0, stream>>>(xyz2, W1, W2, cand, w1t, w2t);
  fused_kernel<<<1024, 256, 0, stream>>>(xyz1, points1, points2, cand, w1t, w2t, b1, b2, out);
}

// Round 4
// 123.121 us; speedup vs baseline: 2.0348x; 1.1215x over previous
//
#include <hip/hip_runtime.h>

#define B_    4
#define N1_   16384
#define N2_   4096
#define C1_   64
#define C2_   128
#define BQ    64            // queries per block
#define WV_   8             // waves per block
#define CHUNK (N2_ / WV_)   // candidates per wave in phase 1 = 512

typedef __attribute__((ext_vector_type(8))) short bf16x8;
typedef __attribute__((ext_vector_type(4))) float f32x4;
typedef __attribute__((ext_vector_type(4))) unsigned short u16x4;

__device__ __forceinline__ unsigned short f2bf(float f) {
  unsigned int u = __builtin_bit_cast(unsigned int, f);
  unsigned int r = (u + 0x7FFFu + ((u >> 16) & 1u)) >> 16;
  return (unsigned short)r;
}

// insert 64-bit lexicographic key x into sorted triple m0<=m1<=m2 (keep 3 smallest)
// fmin/fmax f64 -> v_min_f64/v_max_f64: branchless, no vcc dependency
#define INS3D(x, m0, m1, m2) do {           \
    double _a = fmax((x), (m0));            \
    (m0) = fmin((x), (m0));                 \
    double _b = fmax(_a, (m1));             \
    (m1) = fmin(_a, (m1));                  \
    (m2) = fmin(_b, (m2));                  \
  } while (0)

#define KINF __builtin_bit_cast(double, 0x7FF0000000000000ULL)

// ---- prep: pack candidates (-2x,-2y,-2z,|c|^2), transpose W1/W2 to bf16 ----
__global__ void prep_kernel(const float* __restrict__ xyz2, const float* __restrict__ W1,
                            const float* __restrict__ W2,
                            float4* __restrict__ cand, unsigned short* __restrict__ w1t,
                            unsigned short* __restrict__ w2t) {
  int t = blockIdx.x * 256 + threadIdx.x;
  const int NC  = B_ * N2_;     // 16384
  const int NW1 = 192 * 128;    // 24576
  const int NW2 = 128 * 128;    // 16384
  if (t < NC) {
    float x = xyz2[t * 3 + 0], y = xyz2[t * 3 + 1], z = xyz2[t * 3 + 2];
    cand[t] = make_float4(-2.f * x, -2.f * y, -2.f * z, x * x + y * y + z * z);
  } else if (t < NC + NW1) {
    int i = t - NC; int k = i >> 7, c = i & 127;
    w1t[c * 192 + k] = f2bf(W1[i]);
  } else if (t < NC + NW1 + NW2) {
    int i = t - NC - NW1; int k = i >> 7, c = i & 127;
    w2t[c * 128 + k] = f2bf(W2[i]);
  }
}

// ---- fused: three_nn + interp + concat + MLP(192->128->128) ----
__global__ __launch_bounds__(512, 8) void fused_kernel(
    const float* __restrict__ xyz1, const float* __restrict__ points1,
    const float* __restrict__ points2, const float4* __restrict__ cand,
    const unsigned short* __restrict__ w1t, const unsigned short* __restrict__ w2t,
    const float* __restrict__ bb1, const float* __restrict__ bb2,
    float* __restrict__ out) {

  // union: Ptop (phase1-2) -> Ash (phase3-4) -> Hsh (phase4-5); 25600 B total
  __shared__ __align__(16) unsigned char Ubuf[BQ * 200 * 2];
  unsigned short (*Ash)[200]  = (unsigned short (*)[200])Ubuf;
  double (*Ptop)[BQ][3]       = (double (*)[BQ][3])Ubuf;   // [8][64][3] = 12288 B
  unsigned short (*Hsh)[136]  = (unsigned short (*)[136])Ubuf;
  __shared__ float sW[BQ][3];
  __shared__ int   sJ[BQ][3];

  const int tid  = threadIdx.x;
  const int lane = tid & 63;
  const int wv   = __builtin_amdgcn_readfirstlane(tid >> 6);
  const int bid  = blockIdx.x;
  const int bb   = bid >> 8;            // 256 blocks per batch
  const int n0   = (bid & 255) * BQ;

  // ---------- phase 1: per-wave exact top-3 over its candidate chunk ----------
  const int q = n0 + lane;
  const float* xp = xyz1 + ((size_t)bb * N1_ + q) * 3;
  const float x = xp[0], y = xp[1], z = xp[2];
  const float q1 = fmaf(x, x, fmaf(y, y, z * z));
  const float4* cb = cand + (size_t)bb * N2_;
  const int jbase = wv * CHUNK;

  // 4 independent top-3 streams; key = (d_bits << 32) | idx as double (lexicographic)
  double k0[4], k1[4], k2[4];
  #pragma unroll
  for (int s = 0; s < 4; ++s) { k0[s] = KINF; k1[s] = KINF; k2[s] = KINF; }

  for (int j = 0; j < CHUNK; j += 16) {
    float4 cp[16];
    #pragma unroll
    for (int u = 0; u < 16; ++u) cp[u] = cb[jbase + j + u];
    #pragma unroll
    for (int u = 0; u < 16; ++u) {
      const int s = u & 3;
      // d = |q|^2 - 2 q.c + |c|^2  (cand pre-scaled by -2)
      const float d = fmaf(cp[u].x, x, fmaf(cp[u].y, y, fmaf(cp[u].z, z, q1 + cp[u].w)));
      const unsigned long long kk =
          ((unsigned long long)__builtin_bit_cast(unsigned, d) << 32)
          | (unsigned)(jbase + j + u);
      const double xk = __builtin_bit_cast(double, kk);
      INS3D(xk, k0[s], k1[s], k2[s]);
    }
  }
  // merge 4 streams -> stream 0
  #pragma unroll
  for (int s = 1; s < 4; ++s) {
    INS3D(k0[s], k0[0], k1[0], k2[0]);
    INS3D(k1[s], k0[0], k1[0], k2[0]);
    INS3D(k2[s], k0[0], k1[0], k2[0]);
  }
  Ptop[wv][lane][0] = k0[0]; Ptop[wv][lane][1] = k1[0]; Ptop[wv][lane][2] = k2[0];
  __syncthreads();

  // ---------- phase 2: merge 8 waves' top-3, compute weights ----------
  if (tid < BQ) {
    double m0 = KINF, m1 = KINF, m2 = KINF;
    #pragma unroll
    for (int w = 0; w < WV_; ++w)
      #pragma unroll
      for (int r = 0; r < 3; ++r) {
        const double xk = Ptop[w][tid][r];
        INS3D(xk, m0, m1, m2);
      }
    const unsigned long long u0 = __builtin_bit_cast(unsigned long long, m0);
    const unsigned long long u1 = __builtin_bit_cast(unsigned long long, m1);
    const unsigned long long u2 = __builtin_bit_cast(unsigned long long, m2);
    const float d0 = fmaxf(__builtin_bit_cast(float, (unsigned)(u0 >> 32)), 1e-10f);
    const float d1 = fmaxf(__builtin_bit_cast(float, (unsigned)(u1 >> 32)), 1e-10f);
    const float d2 = fmaxf(__builtin_bit_cast(float, (unsigned)(u2 >> 32)), 1e-10f);
    const float r0 = 1.f / d0, r1 = 1.f / d1, r2 = 1.f / d2;
    const float inorm = 1.f / (r0 + r1 + r2);
    sW[tid][0] = r0 * inorm; sW[tid][1] = r1 * inorm; sW[tid][2] = r2 * inorm;
    sJ[tid][0] = (int)(unsigned)u0; sJ[tid][1] = (int)(unsigned)u1; sJ[tid][2] = (int)(unsigned)u2;
  }
  __syncthreads();

  // ---------- phase 3: gather + interpolate + concat into bf16 A tile ----------
  {
    const int qq = tid >> 3, cq = tid & 7;    // 8 threads per query
    const float w0 = sW[qq][0], w1 = sW[qq][1], w2 = sW[qq][2];
    const float* f0 = points2 + ((size_t)bb * N2_ + sJ[qq][0]) * C2_;
    const float* f1 = points2 + ((size_t)bb * N2_ + sJ[qq][1]) * C2_;
    const float* f2 = points2 + ((size_t)bb * N2_ + sJ[qq][2]) * C2_;
    #pragma unroll
    for (int c = cq * 16; c < cq * 16 + 16; c += 4) {
      const float4 a  = *(const float4*)(f0 + c);
      const float4 bv = *(const float4*)(f1 + c);
      const float4 cv = *(const float4*)(f2 + c);
      u16x4 pk;
      pk.x = f2bf(fmaf(w2, cv.x, fmaf(w1, bv.x, w0 * a.x)));
      pk.y = f2bf(fmaf(w2, cv.y, fmaf(w1, bv.y, w0 * a.y)));
      pk.z = f2bf(fmaf(w2, cv.z, fmaf(w1, bv.z, w0 * a.z)));
      pk.w = f2bf(fmaf(w2, cv.w, fmaf(w1, bv.w, w0 * a.w)));
      *(u16x4*)&Ash[qq][c] = pk;
    }
    const float* p1 = points1 + ((size_t)bb * N1_ + n0 + qq) * C1_;
    #pragma unroll
    for (int c = cq * 8; c < cq * 8 + 8; c += 4) {
      const float4 v = *(const float4*)(p1 + c);
      u16x4 pk;
      pk.x = f2bf(v.x); pk.y = f2bf(v.y); pk.z = f2bf(v.z); pk.w = f2bf(v.w);
      *(u16x4*)&Ash[qq][128 + c] = pk;
    }
  }
  __syncthreads();

  // ---------- phase 4: GEMM1  (64x192) x (192x128), wave = 16-col slice ----------
  const int lr = lane & 15;
  const int lg = lane >> 4;
  const int c0 = wv * 16;
  const int col = c0 + lr;
  f32x4 acc[4];
  #pragma unroll
  for (int m = 0; m < 4; ++m) acc[m] = (f32x4){0.f, 0.f, 0.f, 0.f};

  #pragma unroll
  for (int kk = 0; kk < 6; ++kk) {
    const int kof = kk * 32 + lg * 8;
    const bf16x8 bfr = *(const bf16x8*)(w1t + (size_t)col * 192 + kof);
    #pragma unroll
    for (int m = 0; m < 4; ++m) {
      const bf16x8 af = *(const bf16x8*)&Ash[m * 16 + lr][kof];
      acc[m] = __builtin_amdgcn_mfma_f32_16x16x32_bf16(af, bfr, acc[m], 0, 0, 0);
    }
  }
  __syncthreads();   // all waves done READING Ash before H overwrites the union

  {
    const float bias = bb1[col];
    #pragma unroll
    for (int m = 0; m < 4; ++m)
      #pragma unroll
      for (int e = 0; e < 4; ++e) {
        const int row = m * 16 + lg * 4 + e;
        Hsh[row][col] = f2bf(fmaxf(acc[m][e] + bias, 0.f));
      }
  }
  __syncthreads();

  // ---------- phase 5: GEMM2  (64x128) x (128x128), relu, store f32 ----------
  f32x4 acc2[4];
  #pragma unroll
  for (int m = 0; m < 4; ++m) acc2[m] = (f32x4){0.f, 0.f, 0.f, 0.f};

  #pragma unroll
  for (int kk = 0; kk < 4; ++kk) {
    const int kof = kk * 32 + lg * 8;
    const bf16x8 bfr = *(const bf16x8*)(w2t + (size_t)col * 128 + kof);
    #pragma unroll
    for (int m = 0; m < 4; ++m) {
      const bf16x8 af = *(const bf16x8*)&Hsh[m * 16 + lr][kof];
      acc2[m] = __builtin_amdgcn_mfma_f32_16x16x32_bf16(af, bfr, acc2[m], 0, 0, 0);
    }
  }
  {
    const float bias = bb2[col];
    #pragma unroll
    for (int m = 0; m < 4; ++m)
      #pragma unroll
      for (int e = 0; e < 4; ++e) {
        const int row = m * 16 + lg * 4 + e;
        out[((size_t)bb * N1_ + n0 + row) * 128 + col] = fmaxf(acc2[m][e] + bias, 0.f);
      }
  }
}

extern "C" void kernel_launch(void* const* d_in, const int* in_sizes, int n_in,
                              void* d_out, int out_size, void* d_ws, size_t ws_size,
                              hipStream_t stream) {
  const float* xyz1    = (const float*)d_in[0];
  const float* xyz2    = (const float*)d_in[1];
  const float* points1 = (const float*)d_in[2];
  const float* points2 = (const float*)d_in[3];
  const float* W1      = (const float*)d_in[4];
  const float* b1      = (const float*)d_in[5];
  const float* W2      = (const float*)d_in[6];
  const float* b2      = (const float*)d_in[7];
  float* out = (float*)d_out;

  char* ws = (char*)d_ws;
  float4*         cand = (float4*)ws;                        // 4*4096*16   = 262144 B
  unsigned short* w1t  = (unsigned short*)(ws + 262144);     // 192*128*2   =  49152 B
  unsigned short* w2t  = (unsigned short*)(ws + 311296);     // 128*128*2   =  32768 B

  prep_kernel<<<224, 256, 0, stream>>>(xyz2, W1, W2, cand, w1t, w2t);
  fused_kernel<<<1024, 512, 0, stream>>>(xyz1, points1, points2, cand, w1t, w2t, b1, b2, out);
}